// Round 4
// baseline (9.949 us; speedup 1.0000x reference)
//
#include <hip/hip_runtime.h>
#include <hip/hip_bf16.h>

// Fused antialiased bilinear resize (2,3,345,456) -> (2,3,271,272), fp32.
// Single kernel, 2 horizontally-adjacent outputs per thread:
//  - x windows of ox and ox+1 overlap (xmin advances by d in {1,2}); union is
//    6 columns x 3 rows = 18 loads per pair (9/output vs 12).
//  - y-weight set shared by the pair; store is one coalesced float2.
//  - tap masking by clamped window size kept (right/bottom edge taps have
//    nonzero natural triangle weight but are masked in the aten graph).

#define IW 456
#define IH 345
#define OW 272
#define OH 271
#define BC 6             // batch*channels = 2*3
#define OWP (OW / 2)     // 136 output pairs per row
#define TOTALP (BC * OH * OWP)   // 221136 threads

__global__ __launch_bounds__(256) void resize2d_kernel(
    const float* __restrict__ in, float* __restrict__ out)
{
    int t = blockIdx.x * blockDim.x + threadIdx.x;
    if (t >= TOTALP) return;

    const int oxp = t % OWP;
    const int r   = t / OWP;
    const int oy  = r % OH;
    const int bc  = r / OH;
    const int ox0 = oxp * 2;

    const float SX = (float)IW / (float)OW;   // 1.6764706
    const float RX = (float)OW / (float)IW;   // 0.59649123
    const float SY = (float)IH / (float)OH;   // 1.2730627
    const float RY = (float)OH / (float)IH;   // 0.78550725

    // ---- x weights, output ox0 ----
    float cx0 = ((float)ox0 + 0.5f) * SX;
    int xmin0 = (int)(cx0 - SX + 0.5f); if (xmin0 < 0) xmin0 = 0;
    int xmax0 = (int)(cx0 + SX + 0.5f); if (xmax0 > IW) xmax0 = IW;
    const int xsz0 = xmax0 - xmin0;           // 3 or 4
    float tx0 = (float)xmin0 - cx0 + 0.5f;
    float w00 = 1.0f - fminf(fabsf(tx0 * RX), 1.0f);
    float w01 = 1.0f - fminf(fabsf((tx0 + 1.0f) * RX), 1.0f);
    float w02 = 1.0f - fminf(fabsf((tx0 + 2.0f) * RX), 1.0f);
    float w03 = (xsz0 > 3) ? (1.0f - fminf(fabsf((tx0 + 3.0f) * RX), 1.0f)) : 0.0f;
    float rs0 = __builtin_amdgcn_rcpf(w00 + w01 + w02 + w03);
    w00 *= rs0; w01 *= rs0; w02 *= rs0; w03 *= rs0;

    // ---- x weights, output ox0+1 ----
    float cx1 = cx0 + SX;
    int xmin1 = (int)(cx1 - SX + 0.5f); if (xmin1 < 0) xmin1 = 0;
    int xmax1 = (int)(cx1 + SX + 0.5f); if (xmax1 > IW) xmax1 = IW;
    const int xsz1 = xmax1 - xmin1;
    float tx1 = (float)xmin1 - cx1 + 0.5f;
    float w10 = 1.0f - fminf(fabsf(tx1 * RX), 1.0f);
    float w11 = 1.0f - fminf(fabsf((tx1 + 1.0f) * RX), 1.0f);
    float w12 = 1.0f - fminf(fabsf((tx1 + 2.0f) * RX), 1.0f);
    float w13 = (xsz1 > 3) ? (1.0f - fminf(fabsf((tx1 + 3.0f) * RX), 1.0f)) : 0.0f;
    float rs1 = __builtin_amdgcn_rcpf(w10 + w11 + w12 + w13);
    w10 *= rs1; w11 *= rs1; w12 *= rs1; w13 *= rs1;

    // out1 weights on the union grid (columns xmin0 .. xmin0+5), shift d in {1,2}
    const bool d1 = (xmin1 - xmin0 == 1);
    const float u1 = d1 ? w10 : 0.0f;
    const float u2 = d1 ? w11 : w10;
    const float u3 = d1 ? w12 : w11;
    const float u4 = d1 ? w13 : w12;
    const float u5 = d1 ? 0.0f : w13;

    // ---- y weights (shared by the pair) ----
    float cy = ((float)oy + 0.5f) * SY;
    int ymin = (int)(cy - SY + 0.5f); if (ymin < 0) ymin = 0;
    int ymax = (int)(cy + SY + 0.5f); if (ymax > IH) ymax = IH;
    const int ysz = ymax - ymin;              // 2 or 3
    float ty = (float)ymin - cy + 0.5f;
    float wy0 = 1.0f - fminf(fabsf(ty * RY), 1.0f);
    float wy1 = 1.0f - fminf(fabsf((ty + 1.0f) * RY), 1.0f);
    float wy2 = (ysz > 2) ? (1.0f - fminf(fabsf((ty + 2.0f) * RY), 1.0f)) : 0.0f;
    float rsy = __builtin_amdgcn_rcpf(wy0 + wy1 + wy2);
    wy0 *= rsy; wy1 *= rsy; wy2 *= rsy;

    // ---- gather: 3 rows x 6 union columns ----
    // column clamps: xmin0 <= 452, so +0..+3 are safe; +4,+5 may clamp (w=0 there).
    // row clamps: ymin <= 343, so ymin+1 safe; ymin+2 may clamp (wy2=0 there).
    const int c4 = (xmin0 + 4 > IW - 1) ? (IW - 1) : (xmin0 + 4);
    const int c5 = (xmin0 + 5 > IW - 1) ? (IW - 1) : (xmin0 + 5);
    const int iy2 = (ymin + 2 > IH - 1) ? (IH - 1) : (ymin + 2);

    const float* __restrict__ base = in + (size_t)bc * (IH * IW);
    const float* __restrict__ r0 = base + ymin * IW + xmin0;
    const float* __restrict__ r1 = base + (ymin + 1) * IW + xmin0;
    const float* __restrict__ r2 = base + iy2 * IW + xmin0;
    const int o4 = c4 - xmin0, o5 = c5 - xmin0;

    float acc0, acc1;
    {
        float v0 = r0[0], v1 = r0[1], v2 = r0[2], v3 = r0[3], v4 = r0[o4], v5 = r0[o5];
        float h0 = v0 * w00; h0 = fmaf(v1, w01, h0); h0 = fmaf(v2, w02, h0); h0 = fmaf(v3, w03, h0);
        float h1 = v1 * u1;  h1 = fmaf(v2, u2, h1);  h1 = fmaf(v3, u3, h1);
        h1 = fmaf(v4, u4, h1); h1 = fmaf(v5, u5, h1);
        acc0 = h0 * wy0; acc1 = h1 * wy0;
    }
    {
        float v0 = r1[0], v1 = r1[1], v2 = r1[2], v3 = r1[3], v4 = r1[o4], v5 = r1[o5];
        float h0 = v0 * w00; h0 = fmaf(v1, w01, h0); h0 = fmaf(v2, w02, h0); h0 = fmaf(v3, w03, h0);
        float h1 = v1 * u1;  h1 = fmaf(v2, u2, h1);  h1 = fmaf(v3, u3, h1);
        h1 = fmaf(v4, u4, h1); h1 = fmaf(v5, u5, h1);
        acc0 = fmaf(h0, wy1, acc0); acc1 = fmaf(h1, wy1, acc1);
    }
    {
        float v0 = r2[0], v1 = r2[1], v2 = r2[2], v3 = r2[3], v4 = r2[o4], v5 = r2[o5];
        float h0 = v0 * w00; h0 = fmaf(v1, w01, h0); h0 = fmaf(v2, w02, h0); h0 = fmaf(v3, w03, h0);
        float h1 = v1 * u1;  h1 = fmaf(v2, u2, h1);  h1 = fmaf(v3, u3, h1);
        h1 = fmaf(v4, u4, h1); h1 = fmaf(v5, u5, h1);
        acc0 = fmaf(h0, wy2, acc0); acc1 = fmaf(h1, wy2, acc1);
    }

    float2 res; res.x = acc0; res.y = acc1;
    *(float2*)(out + (size_t)((bc * OH + oy) * OW + ox0)) = res;   // OW even -> 8B aligned
}

extern "C" void kernel_launch(void* const* d_in, const int* in_sizes, int n_in,
                              void* d_out, int out_size, void* d_ws, size_t ws_size,
                              hipStream_t stream) {
    const float* in = (const float*)d_in[0];
    float* out = (float*)d_out;
    const int block = 256;
    const int grid = (TOTALP + block - 1) / block;   // 864
    resize2d_kernel<<<grid, block, 0, stream>>>(in, out);
}